// Round 10
// baseline (74.326 us; speedup 1.0000x reference)
//
#include <hip/hip_runtime.h>

// B=16, S=256, IN=128, OUT=128, HID=512
// y[b,o] = sum_{k=h*128+i} M[b,k]*W2f[k*128+o] + sum_i sx[b,i]*b2[i*128+o]
//   M[b,h,i] = sum_s h[b,s,h]*x[b,s,i],  h = relu(x@W1+b1);  out = y@Wfc + bfc
// 4 kernels: A (x->bf16 + W1T-in-LDS + GEMM1 MFMA + xT/sxp), B (GEMM2 MFMA),
//            C (K=512 split-K f32), D (final reduce).

typedef __attribute__((ext_vector_type(8))) short     s16x8;
typedef __attribute__((ext_vector_type(8))) unsigned short u16x8;
typedef __attribute__((ext_vector_type(4))) float     f32x4;

__device__ __forceinline__ unsigned short f2bf(float f) {
    union { float f; unsigned int u; } v; v.f = f;
    unsigned int r = v.u + 0x7FFFu + ((v.u >> 16) & 1u);   // RNE
    return (unsigned short)(r >> 16);
}
__device__ __forceinline__ float bf2f(unsigned short u) {
    union { unsigned int u; float f; } v; v.u = ((unsigned int)u) << 16;
    return v.f;
}

// ws float offsets
#define OFF_XT   0          // xT   bf16 [16][128][256] -> 262144 f
#define OFF_HT   262144     // hT   bf16 [16][512][256] -> 1048576 f
#define OFF_M    1310720    // M    f32  [16][65536]    -> 1048576 f
#define OFF_PART 2359296    // part f32  [128][16][128] -> 262144 f
#define OFF_SXP  2621440    // sxp  f32  [4][16][128]   -> 8192 f

// ---------- Stage A: hT = relu(x@W1+b1)^T bf16; also xT bf16 + sxp ----------
__global__ __launch_bounds__(256) void k_A(const float* __restrict__ x,
        const float* __restrict__ W1, const float* __restrict__ b1,
        unsigned short* __restrict__ xT, unsigned short* __restrict__ hT,
        float* __restrict__ sxp) {
    __shared__ unsigned short xA[128][136];   // x half-tile bf16 [s][i]; later aliased by hts
    __shared__ unsigned short Ws[128][136];   // W1T slice bf16 [hid][i]
    __shared__ float Wt[128][33];             // f32 transpose staging [i][h-chunk]
    __shared__ float b1s[128];
    const int tid = threadIdx.x;
    const int b = blockIdx.x >> 3, s0h = (blockIdx.x >> 2) & 1, hb = blockIdx.x & 3;

    // stage xA: convert x f32 -> bf16, row-major [s][i]
    {
        const int r = tid >> 1, q = tid & 1;
        const float* xrow = &x[(size_t)(b * 256 + s0h * 128 + r) * 128 + q * 64];
        #pragma unroll
        for (int m = 0; m < 8; ++m) {
            const float4 v0 = *(const float4*)&xrow[m * 8];
            const float4 v1 = *(const float4*)&xrow[m * 8 + 4];
            unsigned short t8[8] __attribute__((aligned(16))) = {
                f2bf(v0.x), f2bf(v0.y), f2bf(v0.z), f2bf(v0.w),
                f2bf(v1.x), f2bf(v1.y), f2bf(v1.z), f2bf(v1.w)};
            *(u16x8*)&xA[r][q * 64 + m * 8] = *(u16x8*)t8;
        }
        if (tid < 128) b1s[tid] = b1[hb * 128 + tid];
    }
    // stage Ws = W1T slice (transpose via f32 LDS chunks of 32 hid)
    for (int hq = 0; hq < 4; ++hq) {
        __syncthreads();
        #pragma unroll
        for (int p = 0; p < 16; ++p) {
            const int flat = p * 256 + tid;
            const int i = flat >> 5, hc = flat & 31;
            Wt[i][hc] = W1[(size_t)i * 512 + hb * 128 + hq * 32 + hc];
        }
        __syncthreads();
        {
            const int h2 = tid >> 3, part = tid & 7;   // h2 0..31, part 0..7
            unsigned short t16[16] __attribute__((aligned(16)));
            #pragma unroll
            for (int m = 0; m < 16; ++m)
                t16[m] = f2bf(Wt[part * 16 + m][h2]);
            *(u16x8*)&Ws[hq * 32 + h2][part * 16]     = *(u16x8*)&t16[0];
            *(u16x8*)&Ws[hq * 32 + h2][part * 16 + 8] = *(u16x8*)&t16[8];
        }
    }
    __syncthreads();

    // GEMM1 (proven): C[tok 128][hid 128], 4 waves of 64x64
    const int w = tid >> 6, lane = tid & 63;
    const int wr = w >> 1, wc = w & 1;
    const int l15 = lane & 15, kl = lane >> 4;
    f32x4 zero = {0.f, 0.f, 0.f, 0.f};
    f32x4 acc[4][4];
    #pragma unroll
    for (int i = 0; i < 4; ++i)
        #pragma unroll
        for (int j = 0; j < 4; ++j) acc[i][j] = zero;
    #pragma unroll
    for (int ks = 0; ks < 4; ++ks) {
        s16x8 a[4], bb[4];
        #pragma unroll
        for (int f = 0; f < 4; ++f) {
            a[f]  = *(const s16x8*)&xA[wr * 64 + f * 16 + l15][ks * 32 + kl * 8];
            bb[f] = *(const s16x8*)&Ws[wc * 64 + f * 16 + l15][ks * 32 + kl * 8];
        }
        #pragma unroll
        for (int fr = 0; fr < 4; ++fr)
            #pragma unroll
            for (int fc = 0; fc < 4; ++fc)
                acc[fr][fc] = __builtin_amdgcn_mfma_f32_16x16x32_bf16(a[fr], bb[fc], acc[fr][fc], 0, 0, 0);
    }
    __syncthreads();

    // hb==0 blocks: emit xT (transposed bf16 x) + sxp from xA before overwrite
    if (hb == 0) {
        const int i = tid >> 1, q = tid & 1;
        float sacc = 0.f;
        unsigned short t64[64] __attribute__((aligned(16)));
        #pragma unroll
        for (int m = 0; m < 64; ++m) {
            const unsigned short u = xA[q * 64 + m][i];
            sacc += bf2f(u);
            t64[m] = u;
        }
        #pragma unroll
        for (int v = 0; v < 8; ++v)
            *(u16x8*)&xT[(size_t)(b * 128 + i) * 256 + s0h * 128 + q * 64 + v * 8] =
                *(u16x8*)&t64[v * 8];
        sxp[(size_t)((s0h * 2 + q) * 16 + b) * 128 + i] = sacc;
    }
    __syncthreads();

    // write hts (relu, bf16, transposed [hid][tok]) into xA region, then out
    unsigned short (*hts)[136] = xA;
    #pragma unroll
    for (int fr = 0; fr < 4; ++fr)
        #pragma unroll
        for (int fc = 0; fc < 4; ++fc)
            #pragma unroll
            for (int j = 0; j < 4; ++j) {
                const int tok = wr * 64 + fr * 16 + kl * 4 + j;
                const int hid = wc * 64 + fc * 16 + l15;
                const float v = acc[fr][fc][j] + b1s[hid];
                hts[hid][tok] = f2bf(v > 0.f ? v : 0.f);
            }
    __syncthreads();
    {
        const int r = tid >> 1, q = tid & 1;
        #pragma unroll
        for (int m = 0; m < 8; ++m)
            *(u16x8*)&hT[(size_t)(b * 512 + hb * 128 + r) * 256 + s0h * 128 + q * 64 + m * 8] =
                *(u16x8*)&hts[r][q * 64 + m * 8];
    }
}

// ---------- Stage B (MFMA): M[b][h][i] = sum_s hT[h][s]*xT[i][s], f32 out ----------
__global__ __launch_bounds__(256) void k_B(const unsigned short* __restrict__ hT,
        const unsigned short* __restrict__ xT, float* __restrict__ M) {
    __shared__ unsigned short hs[128][72];
    __shared__ unsigned short xs[128][72];
    const int tid = threadIdx.x;
    const int b = blockIdx.x >> 2, hb = blockIdx.x & 3;
    const int w = tid >> 6, lane = tid & 63;
    const int wr = w >> 1, wc = w & 1;
    const int l15 = lane & 15, kl = lane >> 4;
    f32x4 zero = {0.f, 0.f, 0.f, 0.f};
    f32x4 acc[4][4];
    #pragma unroll
    for (int i = 0; i < 4; ++i)
        #pragma unroll
        for (int j = 0; j < 4; ++j) acc[i][j] = zero;
    for (int sc = 0; sc < 4; ++sc) {
        __syncthreads();
        {
            const int r = tid >> 1, q = tid & 1;
            #pragma unroll
            for (int m = 0; m < 4; ++m) {
                *(u16x8*)&hs[r][q * 32 + m * 8] =
                    *(const u16x8*)&hT[(size_t)(b * 512 + hb * 128 + r) * 256 + sc * 64 + q * 32 + m * 8];
                *(u16x8*)&xs[r][q * 32 + m * 8] =
                    *(const u16x8*)&xT[(size_t)(b * 128 + r) * 256 + sc * 64 + q * 32 + m * 8];
            }
        }
        __syncthreads();
        #pragma unroll
        for (int ki = 0; ki < 2; ++ki) {
            s16x8 a[4], bb[4];
            #pragma unroll
            for (int f = 0; f < 4; ++f) {
                a[f]  = *(const s16x8*)&hs[wr * 64 + f * 16 + l15][ki * 32 + kl * 8];
                bb[f] = *(const s16x8*)&xs[wc * 64 + f * 16 + l15][ki * 32 + kl * 8];
            }
            #pragma unroll
            for (int fr = 0; fr < 4; ++fr)
                #pragma unroll
                for (int fc = 0; fc < 4; ++fc)
                    acc[fr][fc] = __builtin_amdgcn_mfma_f32_16x16x32_bf16(a[fr], bb[fc], acc[fr][fc], 0, 0, 0);
        }
    }
    #pragma unroll
    for (int fr = 0; fr < 4; ++fr)
        #pragma unroll
        for (int fc = 0; fc < 4; ++fc)
            #pragma unroll
            for (int j = 0; j < 4; ++j) {
                const int h = hb * 128 + wr * 64 + fr * 16 + kl * 4 + j;
                const int i = wc * 64 + fc * 16 + l15;
                M[(size_t)b * 65536 + (size_t)h * 128 + i] = acc[fr][fc][j];
            }
}

// ---------- Stage C: split-K partials of y = M @ W2flat (K=512/block) ----------
__global__ __launch_bounds__(256) void k_C(const float* __restrict__ M,
        const float* __restrict__ W2, float* __restrict__ part) {
    __shared__ float Ms[16][128];
    const int tid = threadIdx.x;
    const int p = blockIdx.x;
    const int o = tid & 127, half = tid >> 7;
    float acc[8] = {};
    for (int sc = 0; sc < 4; ++sc) {
        const int k0 = p * 512 + sc * 128;
        __syncthreads();
        #pragma unroll
        for (int r = 0; r < 8; ++r) {
            const int flat = r * 256 + tid;
            const int b = flat >> 7, kk = flat & 127;
            Ms[b][kk] = M[(size_t)b * 65536 + k0 + kk];
        }
        __syncthreads();
        #pragma unroll 4
        for (int kk = 0; kk < 128; ++kk) {
            const float wv = W2[(size_t)(k0 + kk) * 128 + o];
            #pragma unroll
            for (int j = 0; j < 8; ++j)
                acc[j] += Ms[half * 8 + j][kk] * wv;
        }
    }
    #pragma unroll
    for (int j = 0; j < 8; ++j)
        part[(size_t)(p * 16 + half * 8 + j) * 128 + o] = acc[j];
}

// ---------- Stage D: reduce 128 partials + b2 term + Wfc + bfc ----------
__global__ __launch_bounds__(512) void k_D(const float* __restrict__ part,
        const float* __restrict__ sxp, const float* __restrict__ b2,
        const float* __restrict__ Wfc, const float* __restrict__ bfc,
        float* __restrict__ out) {
    __shared__ float sh[4][128];
    __shared__ float sxs[128];
    __shared__ float ysh[128];
    const int b = blockIdx.x;
    const int t = threadIdx.x & 127;
    const int g = threadIdx.x >> 7;     // 4 groups
    float y = 0.f;
    #pragma unroll 8
    for (int pp = g * 32; pp < g * 32 + 32; ++pp)
        y += part[(size_t)(pp * 16 + b) * 128 + t];
    sh[g][t] = sxp[(size_t)(g * 16 + b) * 128 + t];
    __syncthreads();
    if (g == 0) sxs[t] = sh[0][t] + sh[1][t] + sh[2][t] + sh[3][t];
    __syncthreads();
    #pragma unroll 8
    for (int i = g * 32; i < g * 32 + 32; ++i)
        y += sxs[i] * b2[i * 128 + t];
    sh[g][t] = y;
    __syncthreads();
    if (g == 0) ysh[t] = sh[0][t] + sh[1][t] + sh[2][t] + sh[3][t];
    __syncthreads();
    float o = 0.f;
    #pragma unroll 8
    for (int oo = g * 32; oo < g * 32 + 32; ++oo)
        o += ysh[oo] * Wfc[oo * 128 + t];
    sh[g][t] = o;
    __syncthreads();
    if (g == 0)
        out[b * 128 + t] = bfc[t] + sh[0][t] + sh[1][t] + sh[2][t] + sh[3][t];
}

extern "C" void kernel_launch(void* const* d_in, const int* in_sizes, int n_in,
                              void* d_out, int out_size, void* d_ws, size_t ws_size,
                              hipStream_t stream) {
    const float* x   = (const float*)d_in[0];
    const float* W1  = (const float*)d_in[1];
    const float* b1  = (const float*)d_in[2];
    const float* W2  = (const float*)d_in[3];
    const float* b2  = (const float*)d_in[4];
    const float* Wfc = (const float*)d_in[5];
    const float* bfc = (const float*)d_in[6];
    float* ws  = (float*)d_ws;
    unsigned short* xT = (unsigned short*)(ws + OFF_XT);
    unsigned short* hT = (unsigned short*)(ws + OFF_HT);
    float* M    = ws + OFF_M;
    float* part = ws + OFF_PART;
    float* sxp  = ws + OFF_SXP;
    float* out  = (float*)d_out;

    k_A<<<128, 256, 0, stream>>>(x, W1, b1, xT, hT, sxp);
    k_B<<<64,  256, 0, stream>>>(hT, xT, M);
    k_C<<<128, 256, 0, stream>>>(M, W2, part);
    k_D<<<16,  512, 0, stream>>>(part, sxp, b2, Wfc, bfc, out);
}

// Round 11
// 43.305 us; speedup vs baseline: 1.7163x; 1.7163x over previous
//
#include <hip/hip_runtime.h>

// B=16, S=256, IN=128, OUT=128, HID=512
// y[b,o] = sum_{k=h*128+i} M[b,k]*W2f[k*128+o] + sum_i sx[b,i]*b2[i*128+o]
//   M[b,h,i] = sum_s h[b,s,h]*x[b,s,i],  h = relu(x@W1+b1);  out = y@Wfc + bfc
// 4 kernels: A (x->bf16 + W1T + GEMM1 MFMA + xT/sxp), B (GEMM2 MFMA),
//            C (512-block split-K, float2 W2 stream), D (final, 1024 thr).

typedef __attribute__((ext_vector_type(8))) short     s16x8;
typedef __attribute__((ext_vector_type(8))) unsigned short u16x8;
typedef __attribute__((ext_vector_type(4))) float     f32x4;

__device__ __forceinline__ unsigned short f2bf(float f) {
    union { float f; unsigned int u; } v; v.f = f;
    unsigned int r = v.u + 0x7FFFu + ((v.u >> 16) & 1u);   // RNE
    return (unsigned short)(r >> 16);
}
__device__ __forceinline__ float bf2f(unsigned short u) {
    union { unsigned int u; float f; } v; v.u = ((unsigned int)u) << 16;
    return v.f;
}

// ws float offsets
#define OFF_XT   0          // xT   bf16 [16][128][256] -> 262144 f
#define OFF_HT   262144     // hT   bf16 [16][512][256] -> 1048576 f
#define OFF_M    1310720    // M    f32  [16][65536]    -> 1048576 f
#define OFF_PART 2359296    // part f32  [512][16][128] -> 1048576 f
#define OFF_SXP  3407872    // sxp  f32  [4][16][128]   -> 8192 f

// ---------- Stage A: hT = relu(x@W1+b1)^T bf16; also xT bf16 + sxp ----------
__global__ __launch_bounds__(256) void k_A(const float* __restrict__ x,
        const float* __restrict__ W1, const float* __restrict__ b1,
        unsigned short* __restrict__ xT, unsigned short* __restrict__ hT,
        float* __restrict__ sxp) {
    __shared__ unsigned short xA[128][136];   // x half-tile bf16 [s][i]; later aliased by hts
    __shared__ unsigned short Ws[128][136];   // W1T slice bf16 [hid][i]
    __shared__ float Wt[128][33];             // f32 transpose staging [i][h-chunk]
    __shared__ float b1s[128];
    const int tid = threadIdx.x;
    const int b = blockIdx.x >> 3, s0h = (blockIdx.x >> 2) & 1, hb = blockIdx.x & 3;

    // stage xA: convert x f32 -> bf16, row-major [s][i]
    {
        const int r = tid >> 1, q = tid & 1;
        const float* xrow = &x[(size_t)(b * 256 + s0h * 128 + r) * 128 + q * 64];
        #pragma unroll
        for (int m = 0; m < 8; ++m) {
            const float4 v0 = *(const float4*)&xrow[m * 8];
            const float4 v1 = *(const float4*)&xrow[m * 8 + 4];
            unsigned short t8[8] __attribute__((aligned(16))) = {
                f2bf(v0.x), f2bf(v0.y), f2bf(v0.z), f2bf(v0.w),
                f2bf(v1.x), f2bf(v1.y), f2bf(v1.z), f2bf(v1.w)};
            *(u16x8*)&xA[r][q * 64 + m * 8] = *(u16x8*)t8;
        }
        if (tid < 128) b1s[tid] = b1[hb * 128 + tid];
    }
    // stage Ws = W1T slice (transpose via f32 LDS chunks of 32 hid)
    for (int hq = 0; hq < 4; ++hq) {
        __syncthreads();
        #pragma unroll
        for (int p = 0; p < 16; ++p) {
            const int flat = p * 256 + tid;
            const int i = flat >> 5, hc = flat & 31;
            Wt[i][hc] = W1[(size_t)i * 512 + hb * 128 + hq * 32 + hc];
        }
        __syncthreads();
        {
            const int h2 = tid >> 3, part = tid & 7;   // h2 0..31, part 0..7
            unsigned short t16[16] __attribute__((aligned(16)));
            #pragma unroll
            for (int m = 0; m < 16; ++m)
                t16[m] = f2bf(Wt[part * 16 + m][h2]);
            *(u16x8*)&Ws[hq * 32 + h2][part * 16]     = *(u16x8*)&t16[0];
            *(u16x8*)&Ws[hq * 32 + h2][part * 16 + 8] = *(u16x8*)&t16[8];
        }
    }
    __syncthreads();

    // GEMM1 (proven): C[tok 128][hid 128], 4 waves of 64x64
    const int w = tid >> 6, lane = tid & 63;
    const int wr = w >> 1, wc = w & 1;
    const int l15 = lane & 15, kl = lane >> 4;
    f32x4 zero = {0.f, 0.f, 0.f, 0.f};
    f32x4 acc[4][4];
    #pragma unroll
    for (int i = 0; i < 4; ++i)
        #pragma unroll
        for (int j = 0; j < 4; ++j) acc[i][j] = zero;
    #pragma unroll
    for (int ks = 0; ks < 4; ++ks) {
        s16x8 a[4], bb[4];
        #pragma unroll
        for (int f = 0; f < 4; ++f) {
            a[f]  = *(const s16x8*)&xA[wr * 64 + f * 16 + l15][ks * 32 + kl * 8];
            bb[f] = *(const s16x8*)&Ws[wc * 64 + f * 16 + l15][ks * 32 + kl * 8];
        }
        #pragma unroll
        for (int fr = 0; fr < 4; ++fr)
            #pragma unroll
            for (int fc = 0; fc < 4; ++fc)
                acc[fr][fc] = __builtin_amdgcn_mfma_f32_16x16x32_bf16(a[fr], bb[fc], acc[fr][fc], 0, 0, 0);
    }
    __syncthreads();

    // hb==0 blocks: emit xT (transposed bf16 x) + sxp from xA before overwrite
    if (hb == 0) {
        const int i = tid >> 1, q = tid & 1;
        float sacc = 0.f;
        unsigned short t64[64] __attribute__((aligned(16)));
        #pragma unroll
        for (int m = 0; m < 64; ++m) {
            const unsigned short u = xA[q * 64 + m][i];
            sacc += bf2f(u);
            t64[m] = u;
        }
        #pragma unroll
        for (int v = 0; v < 8; ++v)
            *(u16x8*)&xT[(size_t)(b * 128 + i) * 256 + s0h * 128 + q * 64 + v * 8] =
                *(u16x8*)&t64[v * 8];
        sxp[(size_t)((s0h * 2 + q) * 16 + b) * 128 + i] = sacc;
    }
    __syncthreads();

    // write hts (relu, bf16, transposed [hid][tok]) into xA region, then out
    unsigned short (*hts)[136] = xA;
    #pragma unroll
    for (int fr = 0; fr < 4; ++fr)
        #pragma unroll
        for (int fc = 0; fc < 4; ++fc)
            #pragma unroll
            for (int j = 0; j < 4; ++j) {
                const int tok = wr * 64 + fr * 16 + kl * 4 + j;
                const int hid = wc * 64 + fc * 16 + l15;
                const float v = acc[fr][fc][j] + b1s[hid];
                hts[hid][tok] = f2bf(v > 0.f ? v : 0.f);
            }
    __syncthreads();
    {
        const int r = tid >> 1, q = tid & 1;
        #pragma unroll
        for (int m = 0; m < 8; ++m)
            *(u16x8*)&hT[(size_t)(b * 512 + hb * 128 + r) * 256 + s0h * 128 + q * 64 + m * 8] =
                *(u16x8*)&hts[r][q * 64 + m * 8];
    }
}

// ---------- Stage B (MFMA): M[b][h][i] = sum_s hT[h][s]*xT[i][s], f32 out ----------
__global__ __launch_bounds__(256) void k_B(const unsigned short* __restrict__ hT,
        const unsigned short* __restrict__ xT, float* __restrict__ M) {
    __shared__ unsigned short hs[128][72];
    __shared__ unsigned short xs[128][72];
    const int tid = threadIdx.x;
    const int b = blockIdx.x >> 2, hb = blockIdx.x & 3;
    const int w = tid >> 6, lane = tid & 63;
    const int wr = w >> 1, wc = w & 1;
    const int l15 = lane & 15, kl = lane >> 4;
    f32x4 zero = {0.f, 0.f, 0.f, 0.f};
    f32x4 acc[4][4];
    #pragma unroll
    for (int i = 0; i < 4; ++i)
        #pragma unroll
        for (int j = 0; j < 4; ++j) acc[i][j] = zero;
    for (int sc = 0; sc < 4; ++sc) {
        __syncthreads();
        {
            const int r = tid >> 1, q = tid & 1;
            #pragma unroll
            for (int m = 0; m < 4; ++m) {
                *(u16x8*)&hs[r][q * 32 + m * 8] =
                    *(const u16x8*)&hT[(size_t)(b * 512 + hb * 128 + r) * 256 + sc * 64 + q * 32 + m * 8];
                *(u16x8*)&xs[r][q * 32 + m * 8] =
                    *(const u16x8*)&xT[(size_t)(b * 128 + r) * 256 + sc * 64 + q * 32 + m * 8];
            }
        }
        __syncthreads();
        #pragma unroll
        for (int ki = 0; ki < 2; ++ki) {
            s16x8 a[4], bb[4];
            #pragma unroll
            for (int f = 0; f < 4; ++f) {
                a[f]  = *(const s16x8*)&hs[wr * 64 + f * 16 + l15][ki * 32 + kl * 8];
                bb[f] = *(const s16x8*)&xs[wc * 64 + f * 16 + l15][ki * 32 + kl * 8];
            }
            #pragma unroll
            for (int fr = 0; fr < 4; ++fr)
                #pragma unroll
                for (int fc = 0; fc < 4; ++fc)
                    acc[fr][fc] = __builtin_amdgcn_mfma_f32_16x16x32_bf16(a[fr], bb[fc], acc[fr][fc], 0, 0, 0);
        }
    }
    #pragma unroll
    for (int fr = 0; fr < 4; ++fr)
        #pragma unroll
        for (int fc = 0; fc < 4; ++fc)
            #pragma unroll
            for (int j = 0; j < 4; ++j) {
                const int h = hb * 128 + wr * 64 + fr * 16 + kl * 4 + j;
                const int i = wc * 64 + fc * 16 + l15;
                M[(size_t)b * 65536 + (size_t)h * 128 + i] = acc[fr][fc][j];
            }
}

// ---------- Stage C: split-K partials of y = M @ W2flat (K=128/block, 512 blocks) ----------
// thread: o2 = (tid&63)*2 output cols; g = tid>>6 (wave-uniform) -> b-group of 4.
// W2 loads: float2, 64 lanes x 8B = contiguous 512B/wave. Ms reads wave-uniform broadcast.
__global__ __launch_bounds__(256) void k_C(const float* __restrict__ M,
        const float* __restrict__ W2, float* __restrict__ part) {
    __shared__ float Ms[16][128];
    const int tid = threadIdx.x;
    const int p = blockIdx.x;
    const int k0 = p * 128;
    #pragma unroll
    for (int r = 0; r < 8; ++r) {
        const int flat = r * 256 + tid;
        const int b = flat >> 7, kk = flat & 127;
        Ms[b][kk] = M[(size_t)b * 65536 + k0 + kk];
    }
    __syncthreads();
    const int o2 = (tid & 63) * 2;
    const int g  = tid >> 6;
    float acc[4][2] = {};
    #pragma unroll 8
    for (int kk = 0; kk < 128; ++kk) {
        const float2 w = *(const float2*)&W2[(size_t)(k0 + kk) * 128 + o2];
        #pragma unroll
        for (int bb = 0; bb < 4; ++bb) {
            const float m = Ms[g * 4 + bb][kk];
            acc[bb][0] += m * w.x;
            acc[bb][1] += m * w.y;
        }
    }
    #pragma unroll
    for (int bb = 0; bb < 4; ++bb) {
        float2 v = {acc[bb][0], acc[bb][1]};
        *(float2*)&part[(size_t)(p * 16 + g * 4 + bb) * 128 + o2] = v;
    }
}

// ---------- Stage D: reduce 512 partials + b2 term + Wfc + bfc (1024 thr, 8 groups) ----------
__global__ __launch_bounds__(1024) void k_D(const float* __restrict__ part,
        const float* __restrict__ sxp, const float* __restrict__ b2,
        const float* __restrict__ Wfc, const float* __restrict__ bfc,
        float* __restrict__ out) {
    __shared__ float sh[8][128];
    __shared__ float sxs[128];
    __shared__ float ysum[128];
    __shared__ float ysh[128];
    const int b = blockIdx.x;
    const int t = threadIdx.x & 127;
    const int g = threadIdx.x >> 7;     // 8 groups x 64 partials
    float y = 0.f;
    #pragma unroll 8
    for (int pp = g * 64; pp < g * 64 + 64; ++pp)
        y += part[(size_t)(pp * 16 + b) * 128 + t];
    sh[g][t] = y;
    __syncthreads();
    if (g == 0) {
        float yy = sh[0][t];
        #pragma unroll
        for (int j = 1; j < 8; ++j) yy += sh[j][t];
        ysum[t] = yy;
        sxs[t] = sxp[(size_t)(0 * 16 + b) * 128 + t] + sxp[(size_t)(1 * 16 + b) * 128 + t]
               + sxp[(size_t)(2 * 16 + b) * 128 + t] + sxp[(size_t)(3 * 16 + b) * 128 + t];
    }
    __syncthreads();
    // b2 term: 8 groups x 16 i each
    float yb = 0.f;
    #pragma unroll
    for (int i = g * 16; i < g * 16 + 16; ++i)
        yb += sxs[i] * b2[i * 128 + t];
    sh[g][t] = yb;
    __syncthreads();
    if (g == 0) {
        float yy = ysum[t];
        #pragma unroll
        for (int j = 0; j < 8; ++j) yy += sh[j][t];
        ysh[t] = yy;
    }
    __syncthreads();
    // Wfc: 8 groups x 16 oo each
    float f = 0.f;
    #pragma unroll
    for (int oo = g * 16; oo < g * 16 + 16; ++oo)
        f += ysh[oo] * Wfc[oo * 128 + t];
    sh[g][t] = f;
    __syncthreads();
    if (g == 0) {
        float s = bfc[t];
        #pragma unroll
        for (int j = 0; j < 8; ++j) s += sh[j][t];
        out[b * 128 + t] = s;
    }
}

extern "C" void kernel_launch(void* const* d_in, const int* in_sizes, int n_in,
                              void* d_out, int out_size, void* d_ws, size_t ws_size,
                              hipStream_t stream) {
    const float* x   = (const float*)d_in[0];
    const float* W1  = (const float*)d_in[1];
    const float* b1  = (const float*)d_in[2];
    const float* W2  = (const float*)d_in[3];
    const float* b2  = (const float*)d_in[4];
    const float* Wfc = (const float*)d_in[5];
    const float* bfc = (const float*)d_in[6];
    float* ws  = (float*)d_ws;
    unsigned short* xT = (unsigned short*)(ws + OFF_XT);
    unsigned short* hT = (unsigned short*)(ws + OFF_HT);
    float* M    = ws + OFF_M;
    float* part = ws + OFF_PART;
    float* sxp  = ws + OFF_SXP;
    float* out  = (float*)d_out;

    k_A<<<128, 256, 0, stream>>>(x, W1, b1, xT, hT, sxp);
    k_B<<<64,  256, 0, stream>>>(hT, xT, M);
    k_C<<<512, 256, 0, stream>>>(M, W2, part);
    k_D<<<16,  1024, 0, stream>>>(part, sxp, b2, Wfc, bfc, out);
}

// Round 12
// 34.751 us; speedup vs baseline: 2.1388x; 1.2462x over previous
//
#include <hip/hip_runtime.h>

// B=16, S=256, IN=128, OUT=128, HID=512
// y[b,o] = sum_{k=h*128+i} M[b,k]*W2f[k*128+o] + sum_i sx[b,i]*b2[i*128+o]
//   M[b,h,i] = sum_s h[b,s,h]*x[b,s,i],  h = relu(x@W1+b1);  out = y@Wfc + bfc
// 3 kernels: AB (GEMM1+GEMM2 fused, h never leaves LDS, partial M per s-half),
//            C (512-block split-K, Mp[0]+Mp[1] on load, float2 W2 stream),
//            D (final reduce, 1024 thr).

typedef __attribute__((ext_vector_type(8))) short     s16x8;
typedef __attribute__((ext_vector_type(8))) unsigned short u16x8;
typedef __attribute__((ext_vector_type(4))) float     f32x4;

__device__ __forceinline__ unsigned short f2bf(float f) {
    union { float f; unsigned int u; } v; v.f = f;
    unsigned int r = v.u + 0x7FFFu + ((v.u >> 16) & 1u);   // RNE
    return (unsigned short)(r >> 16);
}
__device__ __forceinline__ float bf2f(unsigned short u) {
    union { unsigned int u; float f; } v; v.u = ((unsigned int)u) << 16;
    return v.f;
}

// ws float offsets
#define OFF_MP   0          // Mp   f32 [2][16][65536] -> 2097152 f
#define OFF_PART 2097152    // part f32 [512][16][128] -> 1048576 f
#define OFF_SXP  3145728    // sxp  f32 [4][16][128]   -> 8192 f

// ---------- Stage AB: GEMM1 (x@W1 -> h in LDS) + GEMM2 (h^T@x -> Mp[sh]) ----------
__global__ __launch_bounds__(256) void k_AB(const float* __restrict__ x,
        const float* __restrict__ W1, const float* __restrict__ b1,
        float* __restrict__ Mp, float* __restrict__ sxp) {
    __shared__ unsigned short xA[128][136];   // x half-tile bf16 [s][i]; aliased by hts after use
    __shared__ unsigned short Ws[128][136];   // W1T slice bf16 [hid][i]
    __shared__ unsigned short xTl[128][136];  // x transposed bf16 [i][s]
    __shared__ float Wt[128][33];             // f32 transpose staging
    __shared__ float b1s[128];
    const int tid = threadIdx.x;
    const int b = blockIdx.x >> 3, sh = (blockIdx.x >> 2) & 1, hb = blockIdx.x & 3;

    // stage xA: convert x f32 -> bf16, row-major [s][i]
    {
        const int r = tid >> 1, q = tid & 1;
        const float* xrow = &x[(size_t)(b * 256 + sh * 128 + r) * 128 + q * 64];
        #pragma unroll
        for (int m = 0; m < 8; ++m) {
            const float4 v0 = *(const float4*)&xrow[m * 8];
            const float4 v1 = *(const float4*)&xrow[m * 8 + 4];
            unsigned short t8[8] __attribute__((aligned(16))) = {
                f2bf(v0.x), f2bf(v0.y), f2bf(v0.z), f2bf(v0.w),
                f2bf(v1.x), f2bf(v1.y), f2bf(v1.z), f2bf(v1.w)};
            *(u16x8*)&xA[r][q * 64 + m * 8] = *(u16x8*)t8;
        }
        if (tid < 128) b1s[tid] = b1[hb * 128 + tid];
    }
    // stage Ws = W1T slice (transpose via f32 LDS chunks of 32 hid)
    for (int hq = 0; hq < 4; ++hq) {
        __syncthreads();
        #pragma unroll
        for (int p = 0; p < 16; ++p) {
            const int flat = p * 256 + tid;
            const int i = flat >> 5, hc = flat & 31;
            Wt[i][hc] = W1[(size_t)i * 512 + hb * 128 + hq * 32 + hc];
        }
        __syncthreads();
        {
            const int h2 = tid >> 3, pt = tid & 7;
            unsigned short t16[16] __attribute__((aligned(16)));
            #pragma unroll
            for (int m = 0; m < 16; ++m)
                t16[m] = f2bf(Wt[pt * 16 + m][h2]);
            *(u16x8*)&Ws[hq * 32 + h2][pt * 16]     = *(u16x8*)&t16[0];
            *(u16x8*)&Ws[hq * 32 + h2][pt * 16 + 8] = *(u16x8*)&t16[8];
        }
    }
    __syncthreads();

    const int w = tid >> 6, lane = tid & 63;
    const int wr = w >> 1, wc = w & 1;
    const int l15 = lane & 15, kl = lane >> 4;
    f32x4 zero = {0.f, 0.f, 0.f, 0.f};

    // GEMM1 (proven): C[tok 128][hid 128]
    f32x4 acc[4][4];
    #pragma unroll
    for (int i = 0; i < 4; ++i)
        #pragma unroll
        for (int j = 0; j < 4; ++j) acc[i][j] = zero;
    #pragma unroll
    for (int ks = 0; ks < 4; ++ks) {
        s16x8 a[4], bb[4];
        #pragma unroll
        for (int f = 0; f < 4; ++f) {
            a[f]  = *(const s16x8*)&xA[wr * 64 + f * 16 + l15][ks * 32 + kl * 8];
            bb[f] = *(const s16x8*)&Ws[wc * 64 + f * 16 + l15][ks * 32 + kl * 8];
        }
        #pragma unroll
        for (int fr = 0; fr < 4; ++fr)
            #pragma unroll
            for (int fc = 0; fc < 4; ++fc)
                acc[fr][fc] = __builtin_amdgcn_mfma_f32_16x16x32_bf16(a[fr], bb[fc], acc[fr][fc], 0, 0, 0);
    }
    __syncthreads();

    // build xTl (local transpose of xA) + sxp partials (hb==0) — BEFORE hts overwrites xA
    {
        const int i = tid >> 1, q = tid & 1;
        float sacc = 0.f;
        unsigned short t64[64] __attribute__((aligned(16)));
        #pragma unroll
        for (int m = 0; m < 64; ++m) {
            const unsigned short u = xA[q * 64 + m][i];
            sacc += bf2f(u);
            t64[m] = u;
        }
        #pragma unroll
        for (int v = 0; v < 8; ++v)
            *(u16x8*)&xTl[i][q * 64 + v * 8] = *(u16x8*)&t64[v * 8];
        if (hb == 0)
            sxp[(size_t)((sh * 2 + q) * 16 + b) * 128 + i] = sacc;
    }
    __syncthreads();

    // write hts (relu, bf16, transposed [hid][tok]) into xA region
    unsigned short (*hts)[136] = xA;
    #pragma unroll
    for (int fr = 0; fr < 4; ++fr)
        #pragma unroll
        for (int fc = 0; fc < 4; ++fc)
            #pragma unroll
            for (int j = 0; j < 4; ++j) {
                const int tok = wr * 64 + fr * 16 + kl * 4 + j;
                const int hid = wc * 64 + fc * 16 + l15;
                const float v = acc[fr][fc][j] + b1s[hid];
                hts[hid][tok] = f2bf(v > 0.f ? v : 0.f);
            }
    __syncthreads();

    // GEMM2 (k_B's proven mapping): Mp[sh][b][hb*128+h][i] = hts @ xTl (contract s=128)
    f32x4 acc2[4][4];
    #pragma unroll
    for (int i = 0; i < 4; ++i)
        #pragma unroll
        for (int j = 0; j < 4; ++j) acc2[i][j] = zero;
    #pragma unroll
    for (int ks = 0; ks < 4; ++ks) {
        s16x8 a[4], bb[4];
        #pragma unroll
        for (int f = 0; f < 4; ++f) {
            a[f]  = *(const s16x8*)&hts[wr * 64 + f * 16 + l15][ks * 32 + kl * 8];
            bb[f] = *(const s16x8*)&xTl[wc * 64 + f * 16 + l15][ks * 32 + kl * 8];
        }
        #pragma unroll
        for (int fr = 0; fr < 4; ++fr)
            #pragma unroll
            for (int fc = 0; fc < 4; ++fc)
                acc2[fr][fc] = __builtin_amdgcn_mfma_f32_16x16x32_bf16(a[fr], bb[fc], acc2[fr][fc], 0, 0, 0);
    }
    const size_t mpbase = (size_t)sh * (16 * 65536) + (size_t)b * 65536;
    #pragma unroll
    for (int fr = 0; fr < 4; ++fr)
        #pragma unroll
        for (int fc = 0; fc < 4; ++fc)
            #pragma unroll
            for (int j = 0; j < 4; ++j) {
                const int h = hb * 128 + wr * 64 + fr * 16 + kl * 4 + j;
                const int i = wc * 64 + fc * 16 + l15;
                Mp[mpbase + (size_t)h * 128 + i] = acc2[fr][fc][j];
            }
}

// ---------- Stage C: split-K partials of y = M @ W2flat (K=128/block, 512 blocks) ----------
__global__ __launch_bounds__(256) void k_C(const float* __restrict__ Mp,
        const float* __restrict__ W2, float* __restrict__ part) {
    __shared__ float Ms[16][128];
    const int tid = threadIdx.x;
    const int p = blockIdx.x;
    const int k0 = p * 128;
    #pragma unroll
    for (int r = 0; r < 8; ++r) {
        const int flat = r * 256 + tid;
        const int b = flat >> 7, kk = flat & 127;
        Ms[b][kk] = Mp[(size_t)b * 65536 + k0 + kk]
                  + Mp[(size_t)(16 + b) * 65536 + k0 + kk];
    }
    __syncthreads();
    const int o2 = (tid & 63) * 2;
    const int g  = tid >> 6;
    float acc[4][2] = {};
    #pragma unroll 8
    for (int kk = 0; kk < 128; ++kk) {
        const float2 w = *(const float2*)&W2[(size_t)(k0 + kk) * 128 + o2];
        #pragma unroll
        for (int bb = 0; bb < 4; ++bb) {
            const float m = Ms[g * 4 + bb][kk];
            acc[bb][0] += m * w.x;
            acc[bb][1] += m * w.y;
        }
    }
    #pragma unroll
    for (int bb = 0; bb < 4; ++bb) {
        float2 v = {acc[bb][0], acc[bb][1]};
        *(float2*)&part[(size_t)(p * 16 + g * 4 + bb) * 128 + o2] = v;
    }
}

// ---------- Stage D: reduce 512 partials + b2 term + Wfc + bfc (1024 thr, 8 groups) ----------
__global__ __launch_bounds__(1024) void k_D(const float* __restrict__ part,
        const float* __restrict__ sxp, const float* __restrict__ b2,
        const float* __restrict__ Wfc, const float* __restrict__ bfc,
        float* __restrict__ out) {
    __shared__ float sh[8][128];
    __shared__ float sxs[128];
    __shared__ float ysum[128];
    __shared__ float ysh[128];
    const int b = blockIdx.x;
    const int t = threadIdx.x & 127;
    const int g = threadIdx.x >> 7;
    float y = 0.f;
    #pragma unroll 8
    for (int pp = g * 64; pp < g * 64 + 64; ++pp)
        y += part[(size_t)(pp * 16 + b) * 128 + t];
    sh[g][t] = y;
    __syncthreads();
    if (g == 0) {
        float yy = sh[0][t];
        #pragma unroll
        for (int j = 1; j < 8; ++j) yy += sh[j][t];
        ysum[t] = yy;
        sxs[t] = sxp[(size_t)(0 * 16 + b) * 128 + t] + sxp[(size_t)(1 * 16 + b) * 128 + t]
               + sxp[(size_t)(2 * 16 + b) * 128 + t] + sxp[(size_t)(3 * 16 + b) * 128 + t];
    }
    __syncthreads();
    float yb = 0.f;
    #pragma unroll
    for (int i = g * 16; i < g * 16 + 16; ++i)
        yb += sxs[i] * b2[i * 128 + t];
    sh[g][t] = yb;
    __syncthreads();
    if (g == 0) {
        float yy = ysum[t];
        #pragma unroll
        for (int j = 0; j < 8; ++j) yy += sh[j][t];
        ysh[t] = yy;
    }
    __syncthreads();
    float f = 0.f;
    #pragma unroll
    for (int oo = g * 16; oo < g * 16 + 16; ++oo)
        f += ysh[oo] * Wfc[oo * 128 + t];
    sh[g][t] = f;
    __syncthreads();
    if (g == 0) {
        float s = bfc[t];
        #pragma unroll
        for (int j = 0; j < 8; ++j) s += sh[j][t];
        out[b * 128 + t] = s;
    }
}

extern "C" void kernel_launch(void* const* d_in, const int* in_sizes, int n_in,
                              void* d_out, int out_size, void* d_ws, size_t ws_size,
                              hipStream_t stream) {
    const float* x   = (const float*)d_in[0];
    const float* W1  = (const float*)d_in[1];
    const float* b1  = (const float*)d_in[2];
    const float* W2  = (const float*)d_in[3];
    const float* b2  = (const float*)d_in[4];
    const float* Wfc = (const float*)d_in[5];
    const float* bfc = (const float*)d_in[6];
    float* ws  = (float*)d_ws;
    float* Mp   = ws + OFF_MP;
    float* part = ws + OFF_PART;
    float* sxp  = ws + OFF_SXP;
    float* out  = (float*)d_out;

    k_AB<<<128, 256, 0, stream>>>(x, W1, b1, Mp, sxp);
    k_C <<<512, 256, 0, stream>>>(Mp, W2, part);
    k_D <<<16, 1024, 0, stream>>>(part, sxp, b2, Wfc, bfc, out);
}

// Round 13
// 34.695 us; speedup vs baseline: 2.1422x; 1.0016x over previous
//
#include <hip/hip_runtime.h>

// B=16, S=256, IN=128, OUT=128, HID=512
// y[b,o] = sum_{k=h*128+i} M[b,k]*W2f[k*128+o] + sum_i sx[b,i]*b2[i*128+o]
//   M[b,h,i] = sum_s h[b,s,h]*x[b,s,i],  h = relu(x@W1+b1);  out = y@Wfc + bfc
// 3 kernels: AB (256 blocks: GEMM1+GEMM2 fused, h in LDS), C (float4 W2 stream),
//            D (final reduce).

typedef __attribute__((ext_vector_type(8))) short     s16x8;
typedef __attribute__((ext_vector_type(8))) unsigned short u16x8;
typedef __attribute__((ext_vector_type(4))) float     f32x4;

__device__ __forceinline__ unsigned short f2bf(float f) {
    union { float f; unsigned int u; } v; v.f = f;
    unsigned int r = v.u + 0x7FFFu + ((v.u >> 16) & 1u);   // RNE
    return (unsigned short)(r >> 16);
}
__device__ __forceinline__ float bf2f(unsigned short u) {
    union { unsigned int u; float f; } v; v.u = ((unsigned int)u) << 16;
    return v.f;
}

// ws float offsets (same footprint as R12, 12.6 MB)
#define OFF_MP   0          // Mp   f32 [2][16][65536] -> 2097152 f
#define OFF_PART 2097152    // part f32 [512][16][128] -> 1048576 f
#define OFF_SXP  3145728    // sxp  f32 [4][16][128]   -> 8192 f

// ---------- Stage AB: GEMM1 (x@W1 -> h in LDS) + GEMM2 (h^T@x -> Mp[sh]) ----------
// 256 blocks: b(16) x hb(8: 64-hid chunk) x sh(2: 128-s half). LDS pool 87 KB:
//   Ws[64][136]   @0      (17408 B)  -- aliased by hts after GEMM1
//   xA[128][136]  @17408  (34816 B)
//   xTl[128][136] @52224  (34816 B)  -- aliases Wt (dead before xTl built)
//   b1s[64]       @87040
__global__ __launch_bounds__(256) void k_AB(const float* __restrict__ x,
        const float* __restrict__ W1, const float* __restrict__ b1,
        float* __restrict__ Mp, float* __restrict__ sxp) {
    __shared__ __align__(16) unsigned char smem[87296];
    auto Ws  = (unsigned short (*)[136])(smem);            // [64][136] hid x i
    auto xA  = (unsigned short (*)[136])(smem + 17408);    // [128][136] s x i
    auto xTl = (unsigned short (*)[136])(smem + 52224);    // [128][136] i x s
    auto Wt  = (float (*)[33])(smem + 52224);              // f32 staging (alias xTl)
    float* b1s = (float*)(smem + 87040);
    auto hts = (unsigned short (*)[136])(smem);            // [64][136] alias Ws

    const int tid = threadIdx.x;
    const int b  = blockIdx.x >> 4;
    const int hb = (blockIdx.x >> 1) & 7;
    const int sh = blockIdx.x & 1;

    // stage xA: x f32 -> bf16, [s 128][i 128]
    {
        const int r = tid >> 1, q = tid & 1;
        const float* xrow = &x[(size_t)(b * 256 + sh * 128 + r) * 128 + q * 64];
        #pragma unroll
        for (int m = 0; m < 8; ++m) {
            const float4 v0 = *(const float4*)&xrow[m * 8];
            const float4 v1 = *(const float4*)&xrow[m * 8 + 4];
            unsigned short t8[8] __attribute__((aligned(16))) = {
                f2bf(v0.x), f2bf(v0.y), f2bf(v0.z), f2bf(v0.w),
                f2bf(v1.x), f2bf(v1.y), f2bf(v1.z), f2bf(v1.w)};
            *(u16x8*)&xA[r][q * 64 + m * 8] = *(u16x8*)t8;
        }
        if (tid < 64) b1s[tid] = b1[hb * 64 + tid];
    }
    // stage Ws = W1T slice [hid 64][i 128] via f32 staging chunks of 32 hid
    for (int hq = 0; hq < 2; ++hq) {
        __syncthreads();
        #pragma unroll
        for (int p = 0; p < 16; ++p) {
            const int flat = p * 256 + tid;
            const int i = flat >> 5, hc = flat & 31;
            Wt[i][hc] = W1[(size_t)i * 512 + hb * 64 + hq * 32 + hc];
        }
        __syncthreads();
        {
            const int h2 = tid >> 3, pt = tid & 7;
            unsigned short t16[16] __attribute__((aligned(16)));
            #pragma unroll
            for (int m = 0; m < 16; ++m)
                t16[m] = f2bf(Wt[pt * 16 + m][h2]);
            *(u16x8*)&Ws[hq * 32 + h2][pt * 16]     = *(u16x8*)&t16[0];
            *(u16x8*)&Ws[hq * 32 + h2][pt * 16 + 8] = *(u16x8*)&t16[8];
        }
    }
    __syncthreads();

    const int w = tid >> 6, lane = tid & 63;
    const int wr = w >> 1, wc = w & 1;
    const int l15 = lane & 15, kl = lane >> 4;
    f32x4 zero = {0.f, 0.f, 0.f, 0.f};

    // GEMM1: C[tok 128][hid 64]; wave tile 64x32
    f32x4 acc[4][2];
    #pragma unroll
    for (int i = 0; i < 4; ++i)
        #pragma unroll
        for (int j = 0; j < 2; ++j) acc[i][j] = zero;
    #pragma unroll
    for (int ks = 0; ks < 4; ++ks) {
        s16x8 a[4], bb[2];
        #pragma unroll
        for (int f = 0; f < 4; ++f)
            a[f] = *(const s16x8*)&xA[wr * 64 + f * 16 + l15][ks * 32 + kl * 8];
        #pragma unroll
        for (int f = 0; f < 2; ++f)
            bb[f] = *(const s16x8*)&Ws[wc * 32 + f * 16 + l15][ks * 32 + kl * 8];
        #pragma unroll
        for (int fr = 0; fr < 4; ++fr)
            #pragma unroll
            for (int fc = 0; fc < 2; ++fc)
                acc[fr][fc] = __builtin_amdgcn_mfma_f32_16x16x32_bf16(a[fr], bb[fc], acc[fr][fc], 0, 0, 0);
    }
    __syncthreads();

    // build xTl (transpose of xA) + sxp partials (hb==0); Wt region is dead
    {
        const int i = tid >> 1, q = tid & 1;
        float sacc = 0.f;
        unsigned short t64[64] __attribute__((aligned(16)));
        #pragma unroll
        for (int m = 0; m < 64; ++m) {
            const unsigned short u = xA[q * 64 + m][i];
            sacc += bf2f(u);
            t64[m] = u;
        }
        #pragma unroll
        for (int v = 0; v < 8; ++v)
            *(u16x8*)&xTl[i][q * 64 + v * 8] = *(u16x8*)&t64[v * 8];
        if (hb == 0)
            sxp[(size_t)((sh * 2 + q) * 16 + b) * 128 + i] = sacc;
    }
    __syncthreads();

    // write hts (relu, bf16, [hid 64][tok 128]) into Ws region (dead after GEMM1)
    #pragma unroll
    for (int fr = 0; fr < 4; ++fr)
        #pragma unroll
        for (int fc = 0; fc < 2; ++fc)
            #pragma unroll
            for (int j = 0; j < 4; ++j) {
                const int tok = wr * 64 + fr * 16 + kl * 4 + j;
                const int hid = wc * 32 + fc * 16 + l15;
                const float v = acc[fr][fc][j] + b1s[hid];
                hts[hid][tok] = f2bf(v > 0.f ? v : 0.f);
            }
    __syncthreads();

    // GEMM2: Mp[sh][b][hb*64+h][i] = hts @ xTl (contract s=128); wave tile 32x64
    f32x4 acc2[2][4];
    #pragma unroll
    for (int i = 0; i < 2; ++i)
        #pragma unroll
        for (int j = 0; j < 4; ++j) acc2[i][j] = zero;
    #pragma unroll
    for (int ks = 0; ks < 4; ++ks) {
        s16x8 a2[2], b2f[4];
        #pragma unroll
        for (int f = 0; f < 2; ++f)
            a2[f] = *(const s16x8*)&hts[wr * 32 + f * 16 + l15][ks * 32 + kl * 8];
        #pragma unroll
        for (int f = 0; f < 4; ++f)
            b2f[f] = *(const s16x8*)&xTl[wc * 64 + f * 16 + l15][ks * 32 + kl * 8];
        #pragma unroll
        for (int fr = 0; fr < 2; ++fr)
            #pragma unroll
            for (int fc = 0; fc < 4; ++fc)
                acc2[fr][fc] = __builtin_amdgcn_mfma_f32_16x16x32_bf16(a2[fr], b2f[fc], acc2[fr][fc], 0, 0, 0);
    }
    const size_t mpbase = (size_t)(sh * 16 + b) * 65536;
    #pragma unroll
    for (int fr = 0; fr < 2; ++fr)
        #pragma unroll
        for (int fc = 0; fc < 4; ++fc)
            #pragma unroll
            for (int j = 0; j < 4; ++j) {
                const int h = hb * 64 + wr * 32 + fr * 16 + kl * 4 + j;
                const int i = wc * 64 + fc * 16 + l15;
                Mp[mpbase + (size_t)h * 128 + i] = acc2[fr][fc][j];
            }
}

// ---------- Stage C: split-K partials of y = M @ W2flat (K=128/block, 512 blocks) ----------
// o4 = (tid&31)*4 output cols (float4); g = tid>>5 -> 2 b-rows per group.
__global__ __launch_bounds__(256) void k_C(const float* __restrict__ Mp,
        const float* __restrict__ W2, float* __restrict__ part) {
    __shared__ float Ms[16][128];
    const int tid = threadIdx.x;
    const int p = blockIdx.x;
    const int k0 = p * 128;
    #pragma unroll
    for (int r = 0; r < 8; ++r) {
        const int flat = r * 256 + tid;
        const int b = flat >> 7, kk = flat & 127;
        Ms[b][kk] = Mp[(size_t)b * 65536 + k0 + kk]
                  + Mp[(size_t)(16 + b) * 65536 + k0 + kk];
    }
    __syncthreads();
    const int o4 = (tid & 31) * 4;
    const int g  = tid >> 5;
    float4 a0 = {0.f, 0.f, 0.f, 0.f}, a1 = a0;
    #pragma unroll 8
    for (int kk = 0; kk < 128; ++kk) {
        const float4 wv = *(const float4*)&W2[(size_t)(k0 + kk) * 128 + o4];
        const float m0 = Ms[g * 2][kk], m1 = Ms[g * 2 + 1][kk];
        a0.x += m0 * wv.x; a0.y += m0 * wv.y; a0.z += m0 * wv.z; a0.w += m0 * wv.w;
        a1.x += m1 * wv.x; a1.y += m1 * wv.y; a1.z += m1 * wv.z; a1.w += m1 * wv.w;
    }
    *(float4*)&part[(size_t)(p * 16 + g * 2) * 128 + o4]     = a0;
    *(float4*)&part[(size_t)(p * 16 + g * 2 + 1) * 128 + o4] = a1;
}

// ---------- Stage D: reduce 512 partials + b2 term + Wfc + bfc (1024 thr, 8 groups) ----------
__global__ __launch_bounds__(1024) void k_D(const float* __restrict__ part,
        const float* __restrict__ sxp, const float* __restrict__ b2,
        const float* __restrict__ Wfc, const float* __restrict__ bfc,
        float* __restrict__ out) {
    __shared__ float sh[8][128];
    __shared__ float sxs[128];
    __shared__ float ysum[128];
    __shared__ float ysh[128];
    const int b = blockIdx.x;
    const int t = threadIdx.x & 127;
    const int g = threadIdx.x >> 7;
    float y = 0.f;
    #pragma unroll 8
    for (int pp = g * 64; pp < g * 64 + 64; ++pp)
        y += part[(size_t)(pp * 16 + b) * 128 + t];
    sh[g][t] = y;
    __syncthreads();
    if (g == 0) {
        float yy = sh[0][t];
        #pragma unroll
        for (int j = 1; j < 8; ++j) yy += sh[j][t];
        ysum[t] = yy;
        sxs[t] = sxp[(size_t)(0 * 16 + b) * 128 + t] + sxp[(size_t)(1 * 16 + b) * 128 + t]
               + sxp[(size_t)(2 * 16 + b) * 128 + t] + sxp[(size_t)(3 * 16 + b) * 128 + t];
    }
    __syncthreads();
    float yb = 0.f;
    #pragma unroll
    for (int i = g * 16; i < g * 16 + 16; ++i)
        yb += sxs[i] * b2[i * 128 + t];
    sh[g][t] = yb;
    __syncthreads();
    if (g == 0) {
        float yy = ysum[t];
        #pragma unroll
        for (int j = 0; j < 8; ++j) yy += sh[j][t];
        ysh[t] = yy;
    }
    __syncthreads();
    float f = 0.f;
    #pragma unroll
    for (int oo = g * 16; oo < g * 16 + 16; ++oo)
        f += ysh[oo] * Wfc[oo * 128 + t];
    sh[g][t] = f;
    __syncthreads();
    if (g == 0) {
        float s = bfc[t];
        #pragma unroll
        for (int j = 0; j < 8; ++j) s += sh[j][t];
        out[b * 128 + t] = s;
    }
}

extern "C" void kernel_launch(void* const* d_in, const int* in_sizes, int n_in,
                              void* d_out, int out_size, void* d_ws, size_t ws_size,
                              hipStream_t stream) {
    const float* x   = (const float*)d_in[0];
    const float* W1  = (const float*)d_in[1];
    const float* b1  = (const float*)d_in[2];
    const float* W2  = (const float*)d_in[3];
    const float* b2  = (const float*)d_in[4];
    const float* Wfc = (const float*)d_in[5];
    const float* bfc = (const float*)d_in[6];
    float* ws  = (float*)d_ws;
    float* Mp   = ws + OFF_MP;
    float* part = ws + OFF_PART;
    float* sxp  = ws + OFF_SXP;
    float* out  = (float*)d_out;

    k_AB<<<256, 256, 0, stream>>>(x, W1, b1, Mp, sxp);
    k_C <<<512, 256, 0, stream>>>(Mp, W2, part);
    k_D <<<16, 1024, 0, stream>>>(part, sxp, b2, Wfc, bfc, out);
}